// Round 1
// baseline (3282.034 us; speedup 1.0000x reference)
//
#include <hip/hip_runtime.h>
#include <cstdint>

typedef _Float16 f16x8 __attribute__((ext_vector_type(8)));
typedef float    f32x4 __attribute__((ext_vector_type(4)));

#define BB 64
#define TT 256
#define EE 512
#define UU 1024
#define NN 3072   // 3*U

#define MFMA16(a, b, c) __builtin_amdgcn_mfma_f32_16x16x32_f16((a), (b), (c), 0, 0, 0)

// ---------------- prep: Wh -> f16 MFMA B-fragment layout ----------------
// WhF[((j*3+g)*32 + kb)*64 + lane][jj] = f16(Wh[kb*32 + quad*8 + jj][g*1024 + j*16 + l16])
__global__ __launch_bounds__(256) void prep_whf(const float* __restrict__ Wh,
                                                _Float16* __restrict__ WhF) {
    int tid  = blockIdx.x * 256 + threadIdx.x;
    int col8 = tid % 384;
    int k    = tid / 384;
    int kb = k >> 5, quad = (k >> 3) & 3, jj = k & 7;
    const float* src = Wh + (long)k * NN + col8 * 8;
#pragma unroll
    for (int i = 0; i < 8; i++) {
        int n   = col8 * 8 + i;
        int g   = n >> 10;
        int nl  = n & 1023;
        int jc  = nl >> 4, l16 = nl & 15;
        int lane = quad * 16 + l16;
        WhF[((((jc * 3 + g) * 32 + kb) * 64 + lane) << 3) + jj] = (_Float16)src[i];
    }
}

__global__ __launch_bounds__(256) void prep_h0(const float* __restrict__ h0,
                                               _Float16* __restrict__ hbuf) {
    int i = blockIdx.x * 256 + threadIdx.x;
    hbuf[i] = (_Float16)h0[i];   // slot 0; dispatch-end release flushes L2 -> visible to bypass loads
}

// ---------------- embed + input projection GEMM (f16 MFMA) ----------------
__global__ __launch_bounds__(256) void proj_kernel(
    const int* __restrict__ tokens, const float* __restrict__ emb,
    const float* __restrict__ Wx, const float* __restrict__ bx,
    _Float16* __restrict__ xproj) {
    int tid  = threadIdx.x;
    int wave = tid >> 6, lane = tid & 63, quad = lane >> 4, l16 = lane & 15;
    int bm = blockIdx.x * 64;
    int bn = blockIdx.y * 128;
    int wm = (wave & 1) * 32, wn = (wave >> 1) * 64;

    int row0 = bm + wm + l16;
    const float* a0p = emb + (long)tokens[row0] * EE;
    const float* a1p = emb + (long)tokens[row0 + 16] * EE;

    f32x4 acc[2][4];
#pragma unroll
    for (int mt = 0; mt < 2; mt++)
#pragma unroll
        for (int nt = 0; nt < 4; nt++) { f32x4 z = {0.f, 0.f, 0.f, 0.f}; acc[mt][nt] = z; }

#pragma unroll 2
    for (int k0 = 0; k0 < EE; k0 += 32) {
        int ka = k0 + quad * 8;
        f16x8 afr[2];
        {
            const float4* p = (const float4*)(a0p + ka);
            float4 x0 = p[0], x1 = p[1];
            afr[0][0] = (_Float16)x0.x; afr[0][1] = (_Float16)x0.y;
            afr[0][2] = (_Float16)x0.z; afr[0][3] = (_Float16)x0.w;
            afr[0][4] = (_Float16)x1.x; afr[0][5] = (_Float16)x1.y;
            afr[0][6] = (_Float16)x1.z; afr[0][7] = (_Float16)x1.w;
        }
        {
            const float4* p = (const float4*)(a1p + ka);
            float4 x0 = p[0], x1 = p[1];
            afr[1][0] = (_Float16)x0.x; afr[1][1] = (_Float16)x0.y;
            afr[1][2] = (_Float16)x0.z; afr[1][3] = (_Float16)x0.w;
            afr[1][4] = (_Float16)x1.x; afr[1][5] = (_Float16)x1.y;
            afr[1][6] = (_Float16)x1.z; afr[1][7] = (_Float16)x1.w;
        }
        f16x8 bfr[4];
#pragma unroll
        for (int nt = 0; nt < 4; nt++) {
            const float* bp = Wx + (long)ka * NN + (bn + wn + nt * 16 + l16);
#pragma unroll
            for (int jj = 0; jj < 8; jj++) bfr[nt][jj] = (_Float16)bp[(long)jj * NN];
        }
#pragma unroll
        for (int mt = 0; mt < 2; mt++)
#pragma unroll
            for (int nt = 0; nt < 4; nt++)
                acc[mt][nt] = MFMA16(afr[mt], bfr[nt], acc[mt][nt]);
    }
#pragma unroll
    for (int mt = 0; mt < 2; mt++) {
        int rowbase = bm + wm + mt * 16 + quad * 4;
#pragma unroll
        for (int nt = 0; nt < 4; nt++) {
            int col = bn + wn + nt * 16 + l16;
            float bias = bx[col];
#pragma unroll
            for (int r = 0; r < 4; r++) {
                int i = rowbase + r;
                int b = i >> 8, t = i & 255;
                xproj[((long)t * BB + b) * NN + col] = (_Float16)(acc[mt][nt][r] + bias);
            }
        }
    }
}

// ---------------- persistent GRU recurrence ----------------
// R3 KEY CHANGE: fence-free cross-XCD handoff.
//  - h is row-partitioned by wave index: wave w of EVERY WG produces and
//    consumes exactly rows [16w,16w+16). So synchronization is per-wave
//    (256 independent byte flags), no __syncthreads in the loop, no atomics,
//    no agent fences (the old REL/ACQ pair = buffer_wbl2 + buffer_inv L2
//    walks per WG per step was the 9.6us/step cost).
//  - producers: write-through f16 stores (sc0 sc1 -> LLC, no dirty L2),
//    s_waitcnt vmcnt(0), then publish byte flag = t+1 (sc0 sc1).
//  - consumers: poll 64 producer flags one-per-lane (1 load covers all),
//    then read h with L2-BYPASS loads (sc0 sc1) -> 2-slot hbuf can never
//    serve stale L2 lines; no invalidates needed.
//  - asm loads are vmcnt-untracked -> manual 16-deep pipeline with counted
//    s_waitcnt vmcnt(8/0) + sched_barrier(0) per 8-frag quarter.
//  - candidate-gate weights (32 frags) moved to LDS (32 KB, contiguous
//    ds_read_b128) to free 128 VGPRs for the load window; z/r gates stay
//    AGPR-pinned (64 frags = 256 AGPRs).
__global__ __launch_bounds__(256, 1) void gru_kernel(
    const _Float16* __restrict__ xproj,    // [T][B][3U]
    const _Float16* __restrict__ WhF,      // fragment layout
    const float* __restrict__ hidden,      // [B][U] fp32 h0
    const float* __restrict__ bh,          // [3U]
    _Float16* __restrict__ hbuf,           // [2][B][U] f16 h exchange
    unsigned char* __restrict__ flags,     // [4 waves][64 WGs] sequence bytes
    float* __restrict__ out) {             // [B][T][U] ++ [B][U]
    __shared__ f16x8 ldsWh[2048];          // 32 KB: candidate-gate frags [kb][lane]
    int tid  = threadIdx.x;
    int wave = tid >> 6, lane = tid & 63, quad = lane >> 4, l16 = lane & 15;
    int j  = blockIdx.x;
    int u  = j * 16 + l16;
    int b0 = wave * 16;

    float bhz = bh[u], bhr = bh[UU + u], bhh = bh[2 * UU + u];

    float hold[4];
#pragma unroll
    for (int r = 0; r < 4; r++) hold[r] = hidden[(long)(b0 + quad * 4 + r) * UU + u];

    // z,r gate weights: 64 frags -> AGPR-pinned (opaque asm producer so the
    // compiler cannot sink the loads back into the t-loop)
    const f16x8* WF = (const f16x8*)WhF + (long)j * 96 * 64 + lane;
    f16x8 w[64];
#pragma unroll
    for (int i = 0; i < 64; i++) w[i] = WF[(long)i * 64];
#pragma unroll
    for (int i = 0; i < 64; i++) asm volatile("" : "+a"(w[i]));

    // candidate-gate weights -> LDS (linear copy of frags 64..95 of this slice)
    {
        const f16x8* src = (const f16x8*)WhF + ((long)j * 96 + 64) * 64;
#pragma unroll
        for (int i = 0; i < 8; i++) ldsWh[i * 256 + tid] = src[i * 256 + tid];
    }
    __syncthreads();   // only barrier in the kernel

    const unsigned char* fq = flags + wave * 64 + lane;  // poll: lane <-> producer WG
    unsigned char* fp       = flags + wave * 64 + j;     // publish: own slot

#pragma unroll 1
    for (int t = 0; t < TT; t++) {
        // ---- x_proj loads first: HBM latency overlaps the flag wait ----
        float xzv[4], xrv[4], xhv[4];
        {
            const _Float16* xp = xproj + (long)t * BB * NN + u;
#pragma unroll
            for (int r = 0; r < 4; r++) {
                const _Float16* p = xp + (long)(b0 + quad * 4 + r) * NN;
                xzv[r] = (float)p[0];
                xrv[r] = (float)p[UU];
                xhv[r] = (float)p[2 * UU];
            }
        }

        // ---- wait until every wave-`wave` producer published step t-1 ----
        if (t) {
            unsigned v;
            for (;;) {
                asm volatile("global_load_ubyte %0, %1, off sc0 sc1\n\ts_waitcnt vmcnt(0)"
                             : "=v"(v) : "v"(fq) : "memory");
                if (v >= (unsigned)t) break;
                __builtin_amdgcn_s_sleep(1);
            }
        }
        // clean vmcnt baseline for the counted waits below (free when t>0:
        // the poll already drained; at t=0 it drains the x loads once)
        asm volatile("s_waitcnt vmcnt(0)" ::: "memory");

        // ---- h loads: L2-bypass, 16-deep window, counted vmcnt ----
        const _Float16* hb = hbuf + (long)(t & 1) * BB * UU
                                  + (long)(b0 + l16) * UU + quad * 8;
        f16x8 hf[16];
#pragma unroll
        for (int kb = 0; kb < 16; kb++)
            asm volatile("global_load_dwordx4 %0, %1, off sc0 sc1"
                         : "=v"(hf[kb]) : "v"(hb + (long)kb * 32));

        f32x4 az = {0.f, 0.f, 0.f, 0.f}, ar = az, ah = az;
#pragma unroll
        for (int q = 0; q < 4; q++) {
            f16x8 whf[8];
#pragma unroll
            for (int i = 0; i < 8; i++) whf[i] = ldsWh[(q * 8 + i) * 64 + lane];
            // outstanding: 16 (q0), 16 (q1), 16 (q2), 8 (q3) -> drain oldest 8
            if (q < 3) asm volatile("s_waitcnt vmcnt(8)" ::: "memory");
            else       asm volatile("s_waitcnt vmcnt(0)" ::: "memory");
            __builtin_amdgcn_sched_barrier(0);   // rule #18: keep MFMAs below the wait
#pragma unroll
            for (int i = 0; i < 8; i++) {
                int kb = q * 8 + i;
                f16x8 afr = hf[kb & 15];
                az = MFMA16(afr, w[kb],      az);
                ar = MFMA16(afr, w[32 + kb], ar);
                ah = MFMA16(afr, whf[i],     ah);
            }
            if (q < 2) {     // refill consumed slots with kb 16..31
#pragma unroll
                for (int i = 0; i < 8; i++) {
                    int kb2 = 16 + q * 8 + i;
                    asm volatile("global_load_dwordx4 %0, %1, off sc0 sc1"
                                 : "=v"(hf[kb2 & 15]) : "v"(hb + (long)kb2 * 32));
                }
            }
        }

        // ---- gate math; publish f16 h BEFORE the fp32 out stores ----
        _Float16* hw = hbuf + (long)((t + 1) & 1) * BB * UU;
        float hn[4];
#pragma unroll
        for (int r = 0; r < 4; r++) {
            float z  = 1.f / (1.f + expf(-(xzv[r] + az[r] + bhz)));
            float rr = 1.f / (1.f + expf(-(xrv[r] + ar[r] + bhr)));
            float cd = tanhf(xhv[r] + rr * (ah[r] + bhh));
            hn[r] = z * hold[r] + (1.f - z) * cd;
            hold[r] = hn[r];
        }
        if (t != TT - 1) {
#pragma unroll
            for (int r = 0; r < 4; r++) {
                int b = b0 + quad * 4 + r;
                unsigned hv = (unsigned)__builtin_bit_cast(unsigned short, (_Float16)hn[r]);
                asm volatile("global_store_short %0, %1, off sc0 sc1"
                             :: "v"(hw + (long)b * UU + u), "v"(hv) : "memory");
            }
            asm volatile("s_waitcnt vmcnt(0)" ::: "memory");   // h at LLC before flag
            if (lane == 0)
                asm volatile("global_store_byte %0, %1, off sc0 sc1"
                             :: "v"(fp), "v"((unsigned)(t + 1)) : "memory");
        }
        // fp32 outputs: plain stores (host-only readers); drain overlaps next poll
#pragma unroll
        for (int r = 0; r < 4; r++) {
            int b = b0 + quad * 4 + r;
            out[(long)b * TT * UU + (long)t * UU + u] = hn[r];
        }
    }
#pragma unroll
    for (int r = 0; r < 4; r++) {
        int b = b0 + quad * 4 + r;
        out[(long)BB * TT * UU + (long)b * UU + u] = hold[r];
    }
}

// ---------------- launch ----------------
extern "C" void kernel_launch(void* const* d_in, const int* in_sizes, int n_in,
                              void* d_out, int out_size, void* d_ws, size_t ws_size,
                              hipStream_t stream) {
    const int*   tokens = (const int*)d_in[0];
    const float* hidden = (const float*)d_in[1];
    const float* emb    = (const float*)d_in[2];
    const float* Wx     = (const float*)d_in[3];
    const float* bx     = (const float*)d_in[4];
    const float* Wh     = (const float*)d_in[5];
    const float* bh     = (const float*)d_in[6];
    float* out = (float*)d_out;

    char* ws = (char*)d_ws;
    _Float16*      xproj = (_Float16*)(ws);                  // 100663296 B
    _Float16*      WhF   = (_Float16*)(ws + 100663296L);     //   6291456 B
    _Float16*      hbuf  = (_Float16*)(ws + 106954752L);     //    262144 B
    unsigned char* flags = (unsigned char*)(ws + 107216896L);//       256 B
    if (ws_size < 107217152UL) return;

    hipMemsetAsync(flags, 0, 256, stream);   // reset sequence flags each launch
    prep_whf<<<1536, 256, 0, stream>>>(Wh, WhF);
    prep_h0<<<256, 256, 0, stream>>>(hidden, hbuf);
    proj_kernel<<<dim3(256, 24), 256, 0, stream>>>(tokens, emb, Wx, bx, xproj);
    gru_kernel<<<64, 256, 0, stream>>>(xproj, WhF, hidden, bh, hbuf, flags, out);
}